// Round 2
// baseline (148.819 us; speedup 1.0000x reference)
//
#include <hip/hip_runtime.h>

// DeepHit loss, MI355X. R=2 risks, B=8192, T=64.
// All integer/bool inputs are delivered as int32 (harness converts).
//
// Pipeline: memset -> prepA (bin counts) -> prepB (prefix, 1 thread)
// -> prepC (counting-sort scatter) -> k_cum (cumsum + event-compacted
// transposed store + likelihood reduce) -> k_rank (dense prefix sigmoid sum,
// event-range split 8 ways) -> k_final.

namespace {
constexpr int R  = 2;
constexpr int Bn = 8192;
constexpr int Tn = 64;
constexpr int NS = 8;                // event-range segments in k_rank
constexpr float ALPHA     = 0.5f;
constexpr float INV_SIGMA = 10.0f;   // 1/0.1
constexpr float EPS       = 1e-8f;
}

__global__ void prepA(const int* __restrict__ tb, const int* __restrict__ ev,
                      int* binE, int* binC) {
    int j = blockIdx.x * blockDim.x + threadIdx.x;
    if (j >= Bn) return;
    int t = tb[j];
    if (ev[j]) atomicAdd(&binE[t], 1);
    else       atomicAdd(&binC[t], 1);
}

__global__ void prepB(const int* __restrict__ binE, const int* __restrict__ binC,
                      int* scatE, int* scatC, int* limE, int* censTotal) {
    if (threadIdx.x == 0) {
        int ae = 0, ac = 0;
        for (int t = 0; t < Tn; ++t) {
            scatE[t] = ae; ae += binE[t]; limE[t] = ae;
            scatC[t] = ac; ac += binC[t];
        }
        *censTotal = ac;
    }
}

__global__ void prepC(const int* __restrict__ tb, const int* __restrict__ ev,
                      int* scatE, int* scatC, int* posE, int* csort) {
    int j = blockIdx.x * blockDim.x + threadIdx.x;
    if (j >= Bn) return;
    int t = tb[j];
    if (ev[j]) {
        posE[j] = atomicAdd(&scatE[t], 1);
    } else {
        int p = atomicAdd(&scatC[t], 1);
        csort[p] = j;
    }
}

__global__ void k_cum(const float* __restrict__ risk, const int* __restrict__ tb,
                      const int* __restrict__ rind, const int* __restrict__ ev,
                      const int* __restrict__ posE,
                      float* __restrict__ cumTs, float* __restrict__ aVal,
                      float* llsum, int* llcnt) {
    int i = blockIdx.x * blockDim.x + threadIdx.x;  // sample
    int r = blockIdx.y;                             // risk
    const float4* row4 = reinterpret_cast<const float4*>(risk + ((size_t)r * Bn + i) * Tn);
    int ti = tb[i];
    bool e = ev[i] != 0;
    float* ct = cumTs + (size_t)r * Tn * Bn + (e ? posE[i] : 0);

    float c = 0.f, a = 0.f, p = 0.f;
#pragma unroll
    for (int q = 0; q < Tn / 4; ++q) {
        float4 vv = row4[q];
        float vs[4] = {vv.x, vv.y, vv.z, vv.w};
#pragma unroll
        for (int u = 0; u < 4; ++u) {
            int t = q * 4 + u;
            c += vs[u];
            if (e) ct[(size_t)t * Bn] = c;      // event columns compacted by posE
            if (t == ti) { a = c; p = vs[u]; }
        }
    }
    aVal[r * Bn + i] = a;

    bool m = e && (rind[i * R + r] != 0);
    float lg = m ? logf(p + EPS) : 0.f;
    int cnt = m ? 1 : 0;
#pragma unroll
    for (int o = 32; o > 0; o >>= 1) {
        lg  += __shfl_down(lg, o, 64);
        cnt += __shfl_down(cnt, o, 64);
    }
    if ((threadIdx.x & 63) == 0) {
        atomicAdd(&llsum[r], lg);
        atomicAdd(&llcnt[r], cnt);
    }
}

__global__ void k_rank(const int* __restrict__ tb, const float* __restrict__ aVal,
                       const float* __restrict__ cumTs, const int* __restrict__ csort,
                       const int* __restrict__ limE, const int* __restrict__ censTotal,
                       float* rlsum) {
    int k = blockIdx.x * blockDim.x + threadIdx.x;
    int r = blockIdx.y;
    int seg = blockIdx.z;
    float s = 0.f;
    int nC = *censTotal;
    int nE = limE[Tn - 1];
    if (k < nC) {
        int i  = csort[k];            // censored sample, sorted by t_i
        int ti = tb[i];
        float a  = aVal[r * Bn + i];
        int lim  = limE[ti];          // events with t_j <= t_i = dense prefix [0,lim)
        const float* rowp = cumTs + ((size_t)r * Tn + ti) * Bn;
        int lo = seg * nE / NS;
        int hi = (seg + 1) * nE / NS;
        if (lim < hi) hi = lim;
#pragma unroll 4
        for (int j = lo; j < hi; ++j) {
            float d = (rowp[j] - a) * INV_SIGMA;      // (cum_j - cum_i)/sigma
            s += __builtin_amdgcn_rcpf(1.f + __expf(d));
        }
    }
#pragma unroll
    for (int o = 32; o > 0; o >>= 1) s += __shfl_down(s, o, 64);
    if ((threadIdx.x & 63) == 0) atomicAdd(&rlsum[r], s);
}

__global__ void k_final(const float* llsum, const int* llcnt, const float* rlsum,
                        float* out) {
    if (threadIdx.x == 0) {
        float total = 0.f;
        for (int r = 0; r < R; ++r) {
            float ll = (llcnt[r] > 0) ? (-llsum[r] / (float)llcnt[r]) : 0.f;
            total += ALPHA * ll + (1.f - ALPHA) * rlsum[r];
        }
        out[0] = total;
    }
}

extern "C" void kernel_launch(void* const* d_in, const int* in_sizes, int n_in,
                              void* d_out, int out_size, void* d_ws, size_t ws_size,
                              hipStream_t stream) {
    const float* risk = (const float*)d_in[0];
    const int* tb     = (const int*)d_in[1];   // int32 on device
    const int* rind   = (const int*)d_in[2];   // bool delivered as int32
    const int* ev     = (const int*)d_in[3];   // bool delivered as int32

    char* ws = (char*)d_ws;
    float* llsum     = (float*)(ws + 0);
    int*   llcnt     = (int*)(ws + 8);
    float* rlsum     = (float*)(ws + 16);
    int*   censTotal = (int*)(ws + 24);
    int*   binE      = (int*)(ws + 64);
    int*   binC      = (int*)(ws + 320);
    int*   scatE     = (int*)(ws + 576);
    int*   scatC     = (int*)(ws + 832);
    int*   limE      = (int*)(ws + 1088);
    int*   posE      = (int*)(ws + 2048);
    int*   csort     = (int*)(ws + 2048 + Bn * 4);
    float* aVal      = (float*)(ws + 2048 + 2 * Bn * 4);
    float* cumTs     = (float*)(ws + 2048 + 2 * Bn * 4 + (size_t)R * Bn * 4);

    hipMemsetAsync(ws, 0, 576, stream);  // accumulators + bin counters

    prepA<<<Bn / 256, 256, 0, stream>>>(tb, ev, binE, binC);
    prepB<<<1, 64, 0, stream>>>(binE, binC, scatE, scatC, limE, censTotal);
    prepC<<<Bn / 256, 256, 0, stream>>>(tb, ev, scatE, scatC, posE, csort);

    dim3 g(Bn / 256, R);
    k_cum<<<g, 256, 0, stream>>>(risk, tb, rind, ev, posE, cumTs, aVal, llsum, llcnt);
    dim3 gr(Bn / 256, R, NS);
    k_rank<<<gr, 256, 0, stream>>>(tb, aVal, cumTs, csort, limE, censTotal, rlsum);
    k_final<<<1, 64, 0, stream>>>(llsum, llcnt, rlsum, (float*)d_out);
}

// Round 3
// 100.421 us; speedup vs baseline: 1.4819x; 1.4819x over previous
//
#include <hip/hip_runtime.h>
#include <math.h>

// DeepHit loss, MI355X. R=2 risks, B=8192, T=64 bins.
// Ints/bools all delivered as int32 by the harness (verified R2: absmax 0).
//
// Pipeline: memset(768B) -> prep1 (1-block LDS histogram + prefix) ->
// prep2 (counting-sort positions) -> k_cum (wave-per-sample shuffle scan,
// event-compacted transposed store + likelihood) -> k_rank (bin-blocked:
// lanes=events in registers, censored loop with uniform scalar 'a') ->
// k_final.

namespace {
constexpr int R  = 2;
constexpr int Bn = 8192;
constexpr int Tn = 64;
constexpr float INV_SIGMA = 10.0f;   // 1/0.1
constexpr float EPS       = 1e-8f;
}

// ws layout (bytes):
// 0     float llsumArr[2][32]
// 256   int   cntArr[2][32]
// 512   float rlsumArr[2][32]
// 768   int limE[64]     (inclusive prefix of event bins)
// 1024  int cbase[64]    (exclusive prefix of censored bins)
// 1280  int ncens[64]
// 1536  int scatEw[64]   (working counters, init = event excl prefix)
// 1792  int scatCw[64]   (working counters, init = cbase)
// 2048  int pos[8192]
// 34816 float aCens[2][8192]
// 100352 float cumTs[2][64][8192]  (event-compacted transposed cumsum rows)

__global__ void prep1(const int* __restrict__ tb, const int* __restrict__ ev,
                      int* limE, int* cbase, int* ncens, int* scatEw, int* scatCw) {
    __shared__ int hE[Tn], hC[Tn];
    int tid = threadIdx.x;
    if (tid < Tn) { hE[tid] = 0; hC[tid] = 0; }
    __syncthreads();
    for (int j = tid; j < Bn; j += 256) {
        int t = tb[j];
        if (ev[j]) atomicAdd(&hE[t], 1);
        else       atomicAdd(&hC[t], 1);
    }
    __syncthreads();
    if (tid == 0) {
        int ae = 0, ac = 0;
        for (int t = 0; t < Tn; ++t) {
            scatEw[t] = ae; ae += hE[t]; limE[t] = ae;
            cbase[t] = ac; scatCw[t] = ac; ncens[t] = hC[t]; ac += hC[t];
        }
    }
}

__global__ void prep2(const int* __restrict__ tb, const int* __restrict__ ev,
                      int* scatEw, int* scatCw, int* pos) {
    int j = blockIdx.x * 256 + threadIdx.x;
    int t = tb[j];
    pos[j] = ev[j] ? atomicAdd(&scatEw[t], 1) : atomicAdd(&scatCw[t], 1);
}

__global__ void k_cum(const float* __restrict__ risk, const int* __restrict__ tb,
                      const int* __restrict__ rind, const int* __restrict__ ev,
                      const int* __restrict__ pos,
                      float* __restrict__ cumTs, float* __restrict__ aCens,
                      float* llsumArr, int* cntArr) {
    int w    = threadIdx.x >> 6;
    int lane = threadIdx.x & 63;
    int idx  = blockIdx.x * 4 + w;      // 0..16383 == r*Bn + i
    int i = idx & (Bn - 1);
    int r = idx >> 13;

    float v = risk[(size_t)idx * Tn + lane];   // coalesced 256B per wave
    float c = v;
#pragma unroll
    for (int o = 1; o < 64; o <<= 1) {         // inclusive wave prefix-scan
        float u = __shfl_up(c, o, 64);
        if (lane >= o) c += u;
    }

    int  ti = tb[i];
    bool e  = ev[i] != 0;
    int  po = pos[i];

    if (e)  // lane 'lane' stores cum at t=lane into transposed compact row
        cumTs[((size_t)(r * Tn + lane)) * Bn + po] = c;

    float a = __shfl(c, ti, 64);
    float p = __shfl(v, ti, 64);
    if (lane == 0) {
        if (e) {
            if (rind[i * R + r]) {
                int slot = r * 32 + (blockIdx.x & 31);
                atomicAdd(&llsumArr[slot], logf(p + EPS));
                atomicAdd(&cntArr[slot], 1);
            }
        } else {
            aCens[r * Bn + po] = a;   // po is global censored-sorted position
        }
    }
}

__global__ void k_rank(const float* __restrict__ cumTs, const float* __restrict__ aCens,
                       const int* __restrict__ limE, const int* __restrict__ cbase,
                       const int* __restrict__ ncens, float* rlsumArr) {
    int t = blockIdx.z, r = blockIdx.y, ec = blockIdx.x;
    int ne = limE[t];
    if (ec * 1024 >= ne) return;
    int nc = ncens[t];
    if (nc == 0) return;

    int j0 = ec * 1024 + threadIdx.x * 4;
    const float* rowp = cumTs + ((size_t)(r * Tn + t)) * Bn;
    float4 c4 = *reinterpret_cast<const float4*>(rowp + j0);
    // pre-scale by 1/sigma; out-of-range events -> +inf => sigmoid term 0
    float c0 = (j0 + 0 < ne) ? c4.x * INV_SIGMA : INFINITY;
    float c1 = (j0 + 1 < ne) ? c4.y * INV_SIGMA : INFINITY;
    float c2 = (j0 + 2 < ne) ? c4.z * INV_SIGMA : INFINITY;
    float c3 = (j0 + 3 < ne) ? c4.w * INV_SIGMA : INFINITY;

    const float* aC = aCens + r * Bn + cbase[t];
    float s0 = 0.f, s1 = 0.f, s2 = 0.f, s3 = 0.f;
#pragma unroll 4
    for (int ii = 0; ii < nc; ++ii) {
        float a10 = aC[ii] * INV_SIGMA;        // wave-uniform load
        s0 += __builtin_amdgcn_rcpf(1.f + __expf(c0 - a10));
        s1 += __builtin_amdgcn_rcpf(1.f + __expf(c1 - a10));
        s2 += __builtin_amdgcn_rcpf(1.f + __expf(c2 - a10));
        s3 += __builtin_amdgcn_rcpf(1.f + __expf(c3 - a10));
    }
    float s = (s0 + s1) + (s2 + s3);
#pragma unroll
    for (int o = 32; o > 0; o >>= 1) s += __shfl_down(s, o, 64);
    if ((threadIdx.x & 63) == 0) {
        int slot = r * 32 + ((blockIdx.z * 8 + blockIdx.x) & 31);
        atomicAdd(&rlsumArr[slot], s);
    }
}

__global__ void k_final(const float* llsumArr, const int* cntArr,
                        const float* rlsumArr, float* out) {
    int lane = threadIdx.x;       // 64 threads; layout [r][32] == [lane]
    float lg = llsumArr[lane];
    float rl = rlsumArr[lane];
    int   cn = cntArr[lane];
#pragma unroll
    for (int o = 1; o <= 16; o <<= 1) {   // reduce within each 32-half
        lg += __shfl_xor(lg, o, 64);
        rl += __shfl_xor(rl, o, 64);
        cn += __shfl_xor(cn, o, 64);
    }
    float lg1 = __shfl(lg, 32, 64);
    float rl1 = __shfl(rl, 32, 64);
    int   cn1 = __shfl(cn, 32, 64);
    if (lane == 0) {
        float ll0 = (cn  > 0) ? (-lg  / (float)cn ) : 0.f;
        float ll1 = (cn1 > 0) ? (-lg1 / (float)cn1) : 0.f;
        out[0] = 0.5f * (ll0 + ll1) + 0.5f * (rl + rl1);
    }
}

extern "C" void kernel_launch(void* const* d_in, const int* in_sizes, int n_in,
                              void* d_out, int out_size, void* d_ws, size_t ws_size,
                              hipStream_t stream) {
    const float* risk = (const float*)d_in[0];
    const int* tb     = (const int*)d_in[1];
    const int* rind   = (const int*)d_in[2];
    const int* ev     = (const int*)d_in[3];

    char* ws = (char*)d_ws;
    float* llsumArr = (float*)(ws + 0);
    int*   cntArr   = (int*)(ws + 256);
    float* rlsumArr = (float*)(ws + 512);
    int*   limE     = (int*)(ws + 768);
    int*   cbase    = (int*)(ws + 1024);
    int*   ncens    = (int*)(ws + 1280);
    int*   scatEw   = (int*)(ws + 1536);
    int*   scatCw   = (int*)(ws + 1792);
    int*   pos      = (int*)(ws + 2048);
    float* aCens    = (float*)(ws + 34816);
    float* cumTs    = (float*)(ws + 100352);

    hipMemsetAsync(ws, 0, 768, stream);   // accumulator slots only

    prep1<<<1, 256, 0, stream>>>(tb, ev, limE, cbase, ncens, scatEw, scatCw);
    prep2<<<Bn / 256, 256, 0, stream>>>(tb, ev, scatEw, scatCw, pos);
    k_cum<<<(Bn * R) / 4 / 64 * 64 / 64, 256, 0, stream>>>(risk, tb, rind, ev, pos,
                                                            cumTs, aCens, llsumArr, cntArr);
    // grid above: (Bn*R)/4 = 4096 blocks of 4 waves
    dim3 gr(8, R, Tn);
    k_rank<<<gr, 256, 0, stream>>>(cumTs, aCens, limE, cbase, ncens, rlsumArr);
    k_final<<<1, 64, 0, stream>>>(llsumArr, cntArr, rlsumArr, (float*)d_out);
}